// Round 6
// baseline (293.777 us; speedup 1.0000x reference)
//
#include <hip/hip_runtime.h>
#include <stdint.h>

// Problem constants (fixed by the reference setup)
#define B_ 32
#define I_ 16384
#define H_ 1024
#define T_ 10
#define M_ 320   // T_*B_  (GEMM M dimension, m = t*32 + b)
#define NW 32    // GEMM per-block n-tile width

typedef __attribute__((ext_vector_type(8))) short short8;  // 8 bf16 (4 VGPRs)
typedef __attribute__((ext_vector_type(4))) float f32x4;
typedef __attribute__((ext_vector_type(4))) unsigned int u32x4;

// ---------------------------------------------------------------------------
// Kernel 1: pack spikes [B][I][T] f32 -> Sbf [M=T*B][I] bf16 (exact: 0/1)
// No LDS: block = (b, i-macro of 512), 640 thr = 10 waves (wave = one t).
// Each block's reads cover one contiguous 20 KB spikes region exactly once
// (L1-resident); writes are perfectly coalesced 16 B/lane.
// ---------------------------------------------------------------------------
__global__ __launch_bounds__(640) void pack_s(const float* __restrict__ spikes,
                                              uint16_t* __restrict__ Sbf) {
  const int b = blockIdx.x & 31, imac = blockIdx.x >> 5;
  const int t = threadIdx.x >> 6, lane = threadIdx.x & 63;
  const int i0 = imac * 512 + lane * 8;
  const float* sp = spikes + (size_t)b * (I_ * T_) + (size_t)i0 * T_ + t;
  unsigned int w[4];
#pragma unroll
  for (int p = 0; p < 4; p++) {
    union { float f; unsigned int u; } c0, c1;
    c0.f = sp[(2 * p) * T_];
    c1.f = sp[(2 * p + 1) * T_];
    w[p] = (c0.u >> 16) | (c1.u & 0xFFFF0000u);  // trunc: exact for 0.0/1.0
  }
  const int m = t * 32 + b;
  *(u32x4*)&Sbf[(size_t)m * I_ + i0] = u32x4{w[0], w[1], w[2], w[3]};
}

// ---------------------------------------------------------------------------
// Kernel 2: GEMM  partial[ks][320][1024] = Sbf * (weight*strength)
// 2-term bf16 split (w = hi + lo), BOTH RNE-rounded — bit-identical numerics
// and accumulation order to the R1-R4 kernels that matched the reference's
// every spike decision (absmax 0.0). DO NOT change the split rounding or the
// per-element MFMA order: the problem sits on a correctness cliff (~1e-5
// margins between v and threshold; R5's trunc-lo flipped a spike).
// NO LDS, NO BARRIERS: every wave autonomous; A and B fragments load
// global->register directly with a depth-2 register pipeline (fine-grained
// per-wave vmcnt waits; no s_waitcnt vmcnt(0) barrier drain can exist).
// Block = 4 waves; wave owns m-rows [80w,80w+80) x NW=32 n (5x2 tiles).
// B (fp32 W,S) re-read by the 4 waves -> L1/L2-served.
// Grid = 32 nt x KS, ks fastest so co-resident blocks share the Sbf slice.
// ---------------------------------------------------------------------------
__global__ __launch_bounds__(256) void gemm(const uint16_t* __restrict__ Sbf,
                                            const float* __restrict__ Wg,
                                            const float* __restrict__ Sg,
                                            float* __restrict__ partial,
                                            int kchunk, int kslog) {
  const int ks = blockIdx.x & ((1 << kslog) - 1);
  const int nt = blockIdx.x >> kslog;
  const int nbase = nt * NW;
  const int tid = threadIdx.x;
  const int lane = tid & 63, wid = tid >> 6;   // wid 0..3
  const int quad = lane >> 4, l15 = lane & 15;
  const int kofs = ks * kchunk;
  const int stages = kchunk >> 5;              // BK = 32 (stages even, >= 4)

  // A fragment base: lane holds A[m][quad*8+j] -> 16B contiguous global
  const uint16_t* ap = Sbf + (size_t)(wid * 80 + l15) * I_ + quad * 8 + kofs;
  // B fp32 base: lane covers (k = quad*8+j, n = nbase+l15+tn*16)
  const size_t boff = (size_t)(kofs + quad * 8) * H_ + nbase + l15;
  const float* wp = Wg + boff;
  const float* sp = Sg + boff;

  f32x4 acc[5][2];
#pragma unroll
  for (int a = 0; a < 5; a++)
#pragma unroll
    for (int b = 0; b < 2; b++) acc[a][b] = f32x4{0.f, 0.f, 0.f, 0.f};

  u32x4 af0[5], af1[5];
  float wv0[2][8], sv0[2][8], wv1[2][8], sv1[2][8];

#define LOADS(af, wv, sv, sk)                                               \
  {                                                                         \
    const size_t ko = (size_t)(sk) * 32;                                    \
    _Pragma("unroll")                                                       \
    for (int tm = 0; tm < 5; tm++)                                          \
      af[tm] = *(const u32x4*)(ap + (size_t)tm * 16 * I_ + ko);             \
    _Pragma("unroll")                                                       \
    for (int tn = 0; tn < 2; tn++)                                          \
      _Pragma("unroll")                                                     \
      for (int j = 0; j < 8; j++) {                                         \
        size_t o = (ko + j) * H_ + tn * 16;                                 \
        wv[tn][j] = wp[o];                                                  \
        sv[tn][j] = sp[o];                                                  \
      }                                                                     \
  }

#define COMPUTE(af, wv, sv)                                                 \
  {                                                                         \
    _Pragma("unroll")                                                       \
    for (int tn = 0; tn < 2; tn++) {                                        \
      unsigned int hw[4], lw[4];                                            \
      _Pragma("unroll")                                                     \
      for (int p = 0; p < 4; p++) {                                         \
        unsigned int hu[2], lu[2];                                          \
        _Pragma("unroll")                                                   \
        for (int e = 0; e < 2; e++) {                                       \
          float pr = wv[tn][2 * p + e] * sv[tn][2 * p + e];                 \
          union { float f; unsigned int u; } cv; cv.f = pr;                 \
          unsigned int r = (cv.u + 0x7FFFu + ((cv.u >> 16) & 1u)) &        \
                           0xFFFF0000u;               /* RNE bf16 hi */     \
          union { unsigned int u; float f; } hv; hv.u = r;                  \
          union { float f; unsigned int u; } cl; cl.f = pr - hv.f; /*exact*/\
          unsigned int rl = (cl.u + 0x7FFFu + ((cl.u >> 16) & 1u)) &       \
                            0xFFFF0000u;              /* RNE bf16 lo */     \
          hu[e] = r; lu[e] = rl;                                            \
        }                                                                   \
        hw[p] = (hu[0] >> 16) | (hu[1] & 0xFFFF0000u);                      \
        lw[p] = (lu[0] >> 16) | (lu[1] & 0xFFFF0000u);                      \
      }                                                                     \
      short8 bhi = __builtin_bit_cast(short8, u32x4{hw[0], hw[1], hw[2], hw[3]}); \
      short8 blo = __builtin_bit_cast(short8, u32x4{lw[0], lw[1], lw[2], lw[3]}); \
      _Pragma("unroll")                                                     \
      for (int tm = 0; tm < 5; tm++) {                                      \
        short8 av = __builtin_bit_cast(short8, af[tm]);                     \
        acc[tm][tn] = __builtin_amdgcn_mfma_f32_16x16x32_bf16(av, bhi, acc[tm][tn], 0, 0, 0); \
        acc[tm][tn] = __builtin_amdgcn_mfma_f32_16x16x32_bf16(av, blo, acc[tm][tn], 0, 0, 0); \
      }                                                                     \
    }                                                                       \
  }

  // depth-2 register pipeline, no barriers anywhere
  LOADS(af0, wv0, sv0, 0);
  LOADS(af1, wv1, sv1, 1);
  int s = 0;
  for (; s + 2 < stages; s += 2) {
    COMPUTE(af0, wv0, sv0);
    LOADS(af0, wv0, sv0, s + 2);
    COMPUTE(af1, wv1, sv1);
    LOADS(af1, wv1, sv1, s + 3);
  }
  COMPUTE(af0, wv0, sv0);
  COMPUTE(af1, wv1, sv1);
#undef LOADS
#undef COMPUTE

  // ---- epilogue: C/D layout col=lane&15, row=quad*4+reg ----
#pragma unroll
  for (int tm = 0; tm < 5; tm++)
#pragma unroll
    for (int tn = 0; tn < 2; tn++) {
      int mrow = wid * 80 + tm * 16 + quad * 4;
      int ncol = nbase + tn * 16 + l15;
      float* dst = partial + ((size_t)ks * M_ + mrow) * H_ + ncol;
      dst[0 * H_] = acc[tm][tn].x;
      dst[1 * H_] = acc[tm][tn].y;
      dst[2 * H_] = acc[tm][tn].z;
      dst[3 * H_] = acc[tm][tn].w;
    }
}

// ---------------------------------------------------------------------------
// Kernel 3: deterministic reduction of K-split partials -> weighted [320][1024]
// Ascending-ks order (bit-identical to R1-R4). Also zeroes the diag region.
// ---------------------------------------------------------------------------
__global__ __launch_bounds__(256) void reduce_w(const float* __restrict__ partial,
                                                float* __restrict__ weighted,
                                                float* __restrict__ out, int KS) {
  if (blockIdx.x == 0 && threadIdx.x < 30) out[327680 + threadIdx.x] = 0.f;
  int j = (blockIdx.x * 256 + threadIdx.x) * 4;
  f32x4 s = f32x4{0.f, 0.f, 0.f, 0.f};
  for (int k = 0; k < KS; k++) {
    f32x4 p = *(const f32x4*)&partial[(size_t)k * (M_ * H_) + j];
    s += p;
  }
  *(f32x4*)&weighted[j] = s;
}

// ---------------------------------------------------------------------------
// Kernel 4: LIF scan, barrier-free. 128 blocks x 64 thr; lane = (bg,hl):
// thread owns h = blk*8+hl and 4 batches (b = bg*4+j). Cross-bg spike-rate
// reduction via shfl_xor(8/16/32) — rate is an exact small integer sum, so
// order is irrelevant; threshold update computed identically
// (deterministically) in the 8 lanes sharing an h.
// ---------------------------------------------------------------------------
__global__ __launch_bounds__(64) void scan(const float* __restrict__ weighted,
                                           const float* __restrict__ threshold,
                                           const float* __restrict__ fre0,
                                           const float* __restrict__ p_tau_mem,
                                           const float* __restrict__ p_tau_syn,
                                           const float* __restrict__ p_target,
                                           const float* __restrict__ p_lr,
                                           float* __restrict__ out) {
  const int lane = threadIdx.x;
  const int hl = lane & 7, bg = lane >> 3;     // 8 h x 8 batch-groups of 4
  const int h = blockIdx.x * 8 + hl;
  const float alpha_mem = expf(-0.001f / p_tau_mem[0]);
  const float alpha_syn = expf(-0.001f / p_tau_syn[0]);
  const float target = p_target[0], lr = p_lr[0];
  float v[4], isyn[4];
#pragma unroll
  for (int j = 0; j < 4; j++) { v[j] = 0.f; isyn[j] = 0.f; }
  float fre = fre0[h];
  float thr = threshold[h];
  for (int t = 0; t < T_; t++) {
    float rsum = 0.f, vsum = 0.f;
#pragma unroll
    for (int j = 0; j < 4; j++) {
      int b = bg * 4 + j;
      float w_in = weighted[(size_t)(t * 32 + b) * H_ + h];
      isyn[j] = alpha_syn * isyn[j] + w_in;
      v[j] = alpha_mem * v[j] + isyn[j];
      float spike = (v[j] >= thr) ? 1.f : 0.f;
      v[j] -= spike * thr;
      out[(size_t)b * (H_ * T_) + (size_t)h * T_ + t] = spike;
      rsum += spike;
      vsum += v[j];
    }
    // sum over the 8 bg-lanes sharing this h (exact: integer-valued)
    float r = rsum;
    r += __shfl_xor(r, 8);
    r += __shfl_xor(r, 16);
    r += __shfl_xor(r, 32);
    float rate = r * (1.f / 32.f);
    fre = 0.99f * fre + 0.01f * rate;          // identical in the 8 lanes
    thr = thr + lr * (fre - target);
    // diagnostics: full-wave sums (vv over 8h x 32b; rr/tt = 8 x per-h value)
    float vv = vsum, rr = rate, tt = thr;
#pragma unroll
    for (int off = 32; off >= 1; off >>= 1) {
      vv += __shfl_xor(vv, off);
      rr += __shfl_xor(rr, off);
      tt += __shfl_xor(tt, off);
    }
    if (lane == 0) {
      atomicAdd(&out[327680 + t], vv * (1.f / 32768.f));  // mem mean over B,H
      atomicAdd(&out[327690 + t], rr * (1.f / 8192.f));   // /(8*1024)
      atomicAdd(&out[327700 + t], tt * (1.f / 8192.f));   // /(8*1024)
    }
  }
}

// ---------------------------------------------------------------------------
extern "C" void kernel_launch(void* const* d_in, const int* in_sizes, int n_in,
                              void* d_out, int out_size, void* d_ws, size_t ws_size,
                              hipStream_t stream) {
  const float* spikes    = (const float*)d_in[0];
  const float* weight    = (const float*)d_in[1];
  const float* strength  = (const float*)d_in[2];
  const float* threshold = (const float*)d_in[3];
  const float* fre0      = (const float*)d_in[4];
  const float* tau_mem   = (const float*)d_in[5];
  const float* tau_syn   = (const float*)d_in[6];
  const float* target    = (const float*)d_in[7];
  const float* lr        = (const float*)d_in[8];
  float* out = (float*)d_out;

  const size_t sbf_bytes = (size_t)M_ * I_ * 2;   // 10.5 MB bf16 A-matrix
  const size_t slice     = (size_t)M_ * H_ * 4;   // 1.31 MB per K-split partial
  int KS = 16, kslog = 4;                         // shrink if ws is small
  while (KS > 1 && sbf_bytes + (size_t)(KS + 1) * slice > ws_size) {
    KS >>= 1; kslog--;
  }

  uint16_t* Sbf   = (uint16_t*)d_ws;
  float* partial  = (float*)((char*)d_ws + sbf_bytes);
  float* weighted = (float*)((char*)d_ws + sbf_bytes + (size_t)KS * slice);

  pack_s<<<32 * (I_ / 512), 640, 0, stream>>>(spikes, Sbf);
  gemm<<<32 * KS, 256, 0, stream>>>(Sbf, weight, strength, partial, I_ / KS, kslog);
  reduce_w<<<(M_ * H_) / 1024, 256, 0, stream>>>(partial, weighted, out, KS);
  scan<<<H_ / 8, 64, 0, stream>>>(weighted, threshold, fre0, tau_mem, tau_syn,
                                  target, lr, out);
}